// Round 1
// baseline (365.242 us; speedup 1.0000x reference)
//
#include <hip/hip_runtime.h>

typedef unsigned short u16;
typedef __bf16 bf16;
typedef bf16 bf16x8 __attribute__((ext_vector_type(8)));
typedef float f32x4 __attribute__((ext_vector_type(4)));
typedef u16 u16x8 __attribute__((ext_vector_type(8)));

#define B_ 4
#define S_ 2048
#define H_ 1024
#define NH_ 16
#define HD_ 64
#define M_TOT (B_ * S_)          // 8192
#define N_TOT (3 * H_)           // 3072

__device__ __forceinline__ u16 f2bf(float f) {
    union { float f; unsigned u; } v; v.f = f;
    unsigned r = v.u + 0x7FFFu + ((v.u >> 16) & 1u);
    return (u16)(r >> 16);
}

// ---------------- fp32 -> bf16 conversion ----------------
__global__ __launch_bounds__(256) void cvt_bf16(const float* __restrict__ src,
                                                u16* __restrict__ dst, int n4) {
    int i = blockIdx.x * blockDim.x + threadIdx.x;
    int stride = gridDim.x * blockDim.x;
    for (; i < n4; i += stride) {
        float4 v = ((const float4*)src)[i];
        u16 o0 = f2bf(v.x), o1 = f2bf(v.y), o2 = f2bf(v.z), o3 = f2bf(v.w);
        u16* p = dst + i * 4;
        p[0] = o0; p[1] = o1; p[2] = o2; p[3] = o3;
    }
}

// ---------------- fused QKV GEMM ----------------
// X: [8192][1024] bf16 (K-major). W: [3072][1024] bf16 (n-major rows, K-major) = [Wq;Wk;Wv].
// C[m][n] = sum_k X[m][k] * W[n][k]  (+bias, Q scaled by log2e/8)
// Output layout per buffer: [B][NH][S][HD] bf16.
#define BK 32
#define LDT 40   // padded LDS stride (elems); 80 B rows keep 16B alignment, 2-way bank conflicts only

__global__ __launch_bounds__(256) void qkv_gemm(
    const u16* __restrict__ X, const u16* __restrict__ W,
    const float* __restrict__ bq, const float* __restrict__ bk, const float* __restrict__ bv,
    u16* __restrict__ Q, u16* __restrict__ Ko, u16* __restrict__ Vo) {
    __shared__ __align__(16) u16 As[128 * LDT];
    __shared__ __align__(16) u16 Bs[128 * LDT];

    const int tid = threadIdx.x;
    const int lane = tid & 63;
    const int wave = tid >> 6;
    const int m0 = blockIdx.y * 128;
    const int n0 = blockIdx.x * 128;
    const int wr = (wave >> 1) * 64;   // wave row offset in tile
    const int wc = (wave & 1) * 64;    // wave col offset in tile

    f32x4 acc[4][4];
#pragma unroll
    for (int m = 0; m < 4; m++)
#pragma unroll
        for (int n = 0; n < 4; n++) acc[m][n] = (f32x4){0.f, 0.f, 0.f, 0.f};

    // staging: 128 rows x 32 elems = 512 x 16B chunks per operand; each thread: 2 chunks each
    const int r0 = tid >> 2;            // 0..63
    const int kq = (tid & 3) * 8;       // elem offset 0,8,16,24

    const int row_a = lane & 15;
    const int ko = (lane >> 4) * 8;

    for (int k0 = 0; k0 < H_; k0 += BK) {
        __syncthreads();
        *(u16x8*)&As[r0 * LDT + kq]        = *(const u16x8*)&X[(m0 + r0) * H_ + k0 + kq];
        *(u16x8*)&As[(r0 + 64) * LDT + kq] = *(const u16x8*)&X[(m0 + r0 + 64) * H_ + k0 + kq];
        *(u16x8*)&Bs[r0 * LDT + kq]        = *(const u16x8*)&W[(n0 + r0) * H_ + k0 + kq];
        *(u16x8*)&Bs[(r0 + 64) * LDT + kq] = *(const u16x8*)&W[(n0 + r0 + 64) * H_ + k0 + kq];
        __syncthreads();

        bf16x8 a[4], bfr[4];
#pragma unroll
        for (int m = 0; m < 4; m++)
            a[m] = *(const bf16x8*)&As[(wr + m * 16 + row_a) * LDT + ko];
#pragma unroll
        for (int n = 0; n < 4; n++)
            bfr[n] = *(const bf16x8*)&Bs[(wc + n * 16 + row_a) * LDT + ko];
#pragma unroll
        for (int m = 0; m < 4; m++)
#pragma unroll
            for (int n = 0; n < 4; n++)
                acc[m][n] = __builtin_amdgcn_mfma_f32_16x16x32_bf16(a[m], bfr[n], acc[m][n], 0, 0, 0);
    }

    // epilogue: scatter to Q/K/V in [B][NH][S][HD]; fold (1/sqrt(HD))*log2(e) into Q
    const float QS = 0.125f * 1.44269504f;
#pragma unroll
    for (int n = 0; n < 4; n++) {
        int ng = n0 + wc + n * 16 + (lane & 15);   // 0..3071
        int which = ng >> 10;                       // 0=q 1=k 2=v (uniform per frag)
        int nn = ng & 1023;
        const float* bp = (which == 0) ? bq : (which == 1) ? bk : bv;
        float bias = bp[nn];
        float scale = (which == 0) ? QS : 1.0f;
        u16* dst = (which == 0) ? Q : (which == 1) ? Ko : Vo;
        int h = nn >> 6, d = nn & 63;
#pragma unroll
        for (int m = 0; m < 4; m++) {
#pragma unroll
            for (int j = 0; j < 4; j++) {
                int mg = m0 + wr + m * 16 + (lane >> 4) * 4 + j;   // global row
                int bb = mg >> 11, s = mg & 2047;
                float v = (acc[m][n][j] + bias) * scale;
                dst[(((bb * NH_ + h) * S_) + s) * HD_ + d] = f2bf(v);
            }
        }
    }
}

// ---------------- flash attention ----------------
// Q,K,V: [B][NH][S][HD] bf16; Q pre-scaled by log2e/8. mask: [B][S] fp32 additive.
// out: [B][S][H] fp32. Block: 4 waves x 16 q-rows = 64 q-rows; KV tile = 64.
#define KVB 64
#define LV 72   // padded LDS stride

__global__ __launch_bounds__(256) void attn(
    const u16* __restrict__ Q, const u16* __restrict__ K, const u16* __restrict__ V,
    const float* __restrict__ mask, float* __restrict__ out) {
    const int head = blockIdx.y;            // 0..63
    const int b = head >> 4, h = head & 15;
    const int q0 = blockIdx.x * 64;
    const int tid = threadIdx.x;
    const int lane = tid & 63;
    const int wave = tid >> 6;

    const u16* Qh = Q + (size_t)head * S_ * HD_;
    const u16* Kh = K + (size_t)head * S_ * HD_;
    const u16* Vh = V + (size_t)head * S_ * HD_;

    __shared__ __align__(16) u16 Kl[KVB][LV];
    __shared__ __align__(16) u16 Vt[HD_][LV];
    __shared__ __align__(16) u16 P[4][16][LV];

    const int ko = (lane >> 4) * 8;
    const int qr = q0 + wave * 16 + (lane & 15);
    bf16x8 qf0 = *(const bf16x8*)&Qh[qr * HD_ + ko];
    bf16x8 qf1 = *(const bf16x8*)&Qh[qr * HD_ + 32 + ko];

    f32x4 acc_o[4];
#pragma unroll
    for (int n = 0; n < 4; n++) acc_o[n] = (f32x4){0.f, 0.f, 0.f, 0.f};
    float mj[4], lj[4];
#pragma unroll
    for (int j = 0; j < 4; j++) { mj[j] = -1e30f; lj[j] = 0.f; }

    const int sr = tid >> 2;           // staging row 0..63
    const int sd = (tid & 3) * 16;     // 0,16,32,48
    const float LOG2E = 1.44269504f;

    for (int kv0 = 0; kv0 < S_; kv0 += KVB) {
        __syncthreads();
        // stage K row-major
        *(u16x8*)&Kl[sr][sd]     = *(const u16x8*)&Kh[(kv0 + sr) * HD_ + sd];
        *(u16x8*)&Kl[sr][sd + 8] = *(const u16x8*)&Kh[(kv0 + sr) * HD_ + sd + 8];
        // stage V transposed: Vt[d][kv]
        u16x8 wa = *(const u16x8*)&Vh[(kv0 + sr) * HD_ + sd];
        u16x8 wb = *(const u16x8*)&Vh[(kv0 + sr) * HD_ + sd + 8];
#pragma unroll
        for (int e = 0; e < 8; e++) { Vt[sd + e][sr] = wa[e]; Vt[sd + 8 + e][sr] = wb[e]; }
        __syncthreads();

        // scores: S2[q][kv] = (Q*log2e/8)·K + mask*log2e
        f32x4 s[4];
#pragma unroll
        for (int n = 0; n < 4; n++) {
            f32x4 c = (f32x4){0.f, 0.f, 0.f, 0.f};
            bf16x8 kb0 = *(const bf16x8*)&Kl[n * 16 + (lane & 15)][ko];
            bf16x8 kb1 = *(const bf16x8*)&Kl[n * 16 + (lane & 15)][32 + ko];
            c = __builtin_amdgcn_mfma_f32_16x16x32_bf16(qf0, kb0, c, 0, 0, 0);
            c = __builtin_amdgcn_mfma_f32_16x16x32_bf16(qf1, kb1, c, 0, 0, 0);
            float mv = mask[b * S_ + kv0 + n * 16 + (lane & 15)] * LOG2E;
#pragma unroll
            for (int j = 0; j < 4; j++) c[j] += mv;
            s[n] = c;
        }
        // row max (rows live on 16-lane groups)
        float tm[4];
#pragma unroll
        for (int j = 0; j < 4; j++)
            tm[j] = fmaxf(fmaxf(s[0][j], s[1][j]), fmaxf(s[2][j], s[3][j]));
#pragma unroll
        for (int dx = 1; dx < 16; dx <<= 1)
#pragma unroll
            for (int j = 0; j < 4; j++) tm[j] = fmaxf(tm[j], __shfl_xor(tm[j], dx, 64));

        float fac[4], rs[4];
#pragma unroll
        for (int j = 0; j < 4; j++) {
            float mn = fmaxf(mj[j], tm[j]);
            fac[j] = exp2f(mj[j] - mn);
            mj[j] = mn;
            rs[j] = 0.f;
        }
        // P = 2^(s - m), store bf16 to per-wave LDS tile [qrow][kv]
#pragma unroll
        for (int n = 0; n < 4; n++)
#pragma unroll
            for (int j = 0; j < 4; j++) {
                float p = exp2f(s[n][j] - mj[j]);
                rs[j] += p;
                P[wave][(lane >> 4) * 4 + j][n * 16 + (lane & 15)] = f2bf(p);
            }
#pragma unroll
        for (int dx = 1; dx < 16; dx <<= 1)
#pragma unroll
            for (int j = 0; j < 4; j++) rs[j] += __shfl_xor(rs[j], dx, 64);
#pragma unroll
        for (int j = 0; j < 4; j++) lj[j] = lj[j] * fac[j] + rs[j];
#pragma unroll
        for (int n = 0; n < 4; n++)
#pragma unroll
            for (int j = 0; j < 4; j++) acc_o[n][j] *= fac[j];

        // PV: ctx += P(16xKVB) @ V(KVBxHD)
#pragma unroll
        for (int n = 0; n < 4; n++) {
            bf16x8 pf0 = *(const bf16x8*)&P[wave][lane & 15][ko];
            bf16x8 pf1 = *(const bf16x8*)&P[wave][lane & 15][32 + ko];
            bf16x8 vf0 = *(const bf16x8*)&Vt[n * 16 + (lane & 15)][ko];
            bf16x8 vf1 = *(const bf16x8*)&Vt[n * 16 + (lane & 15)][32 + ko];
            acc_o[n] = __builtin_amdgcn_mfma_f32_16x16x32_bf16(pf0, vf0, acc_o[n], 0, 0, 0);
            acc_o[n] = __builtin_amdgcn_mfma_f32_16x16x32_bf16(pf1, vf1, acc_o[n], 0, 0, 0);
        }
    }

    // epilogue: out[b][s][h*64+d] = acc/l
#pragma unroll
    for (int n = 0; n < 4; n++)
#pragma unroll
        for (int j = 0; j < 4; j++) {
            int row = q0 + wave * 16 + (lane >> 4) * 4 + j;
            float v = acc_o[n][j] / lj[j];
            out[(b * S_ + row) * H_ + h * HD_ + n * 16 + (lane & 15)] = v;
        }
}

// ---------------- launch ----------------
extern "C" void kernel_launch(void* const* d_in, const int* in_sizes, int n_in,
                              void* d_out, int out_size, void* d_ws, size_t ws_size,
                              hipStream_t stream) {
    const float* hs   = (const float*)d_in[0];
    const float* mask = (const float*)d_in[1];
    const float* wq   = (const float*)d_in[2];
    const float* bq   = (const float*)d_in[3];
    const float* wk   = (const float*)d_in[4];
    const float* bk   = (const float*)d_in[5];
    const float* wv   = (const float*)d_in[6];
    const float* bv   = (const float*)d_in[7];
    float* out = (float*)d_out;

    char* ws = (char*)d_ws;
    u16* Xb = (u16*)ws;                                   // 8192*1024*2   = 16 MB
    u16* Wb = (u16*)(ws + 16777216);                      // 3072*1024*2   = 6 MB
    u16* Qb = (u16*)(ws + 23068672);                      // 16 MB
    u16* Kb = (u16*)(ws + 39845888);                      // 16 MB
    u16* Vb = (u16*)(ws + 56623104);                      // 16 MB (end 73400320)

    cvt_bf16<<<1024, 256, 0, stream>>>(hs, Xb, (M_TOT * H_) / 4);
    cvt_bf16<<<512, 256, 0, stream>>>(wq, Wb,                (H_ * H_) / 4);
    cvt_bf16<<<512, 256, 0, stream>>>(wk, Wb + H_ * H_,      (H_ * H_) / 4);
    cvt_bf16<<<512, 256, 0, stream>>>(wv, Wb + 2 * H_ * H_,  (H_ * H_) / 4);

    qkv_gemm<<<dim3(N_TOT / 128, M_TOT / 128), 256, 0, stream>>>(
        Xb, Wb, bq, bk, bv, Qb, Kb, Vb);

    attn<<<dim3(S_ / 64, B_ * NH_), 256, 0, stream>>>(Qb, Kb, Vb, mask, out);
}